// Round 2
// baseline (259.742 us; speedup 1.0000x reference)
//
#include <hip/hip_runtime.h>

// ---------------------------------------------------------------------------
// ActorCritic fused loss, MI355X — single full-data pass + hierarchical scan.
//   T=8192, B=4096.
//   k_detect  : mask dtype probe (int32 {0,1} vs 1-byte bool)
//   k_pass1   : ONE pass over all 5 inputs. Per chunk of L timesteps:
//               chunk-local discounted returns Gl (Horner), 10 masked base
//               sums (using Gl), 5 correction coefficients capturing the
//               linear dependence of each sum on the chunk-entry carry H:
//                 G_t = Gl_t + w_t * H_c,  w_t = gamma^(L-i)
//   k_pass2a  : fold NC chunks into GC=32 groups; per (group,col) compute
//               group carry Sg and {A,B,C} response coefficients
//               (corr = A + H_enter*B + H_enter^2*C for the G^2 term).
//   k_pass2b  : 32-step group scan per column, accumulate 4 corrections.
//   k_final   : combine block partials + corrections, closed-form losses.
// ---------------------------------------------------------------------------

constexpr int T   = 8192;
constexpr int B   = 4096;
constexpr int B4  = B / 4;
constexpr int BLK = 256;
constexpr int WAVES = BLK / 64;
constexpr int GC  = 32;              // pass-2 chunk groups (T/GC = 256 steps/group)
constexpr int GCB = GC * B;          // plane size (floats) for pass2a outputs
constexpr int NB2 = B / BLK;         // pass2b blocks (16)
constexpr float GAMMA_F = 0.99f;

constexpr double cpow(double g, int n) { double r = 1.0; for (int i = 0; i < n; ++i) r *= g; return r; }
constexpr float GLNG = (float)cpow(0.99, T / GC);   // gamma^(L*NG) group transfer

// --------------------------------------------------------------------------
// Probe mask layout: int32 {0,1} has bytes 1..3 of every element == 0.
__global__ void __launch_bounds__(BLK) k_detect(const unsigned char* __restrict__ m,
                                                int* __restrict__ flag) {
    __shared__ unsigned sh[WAVES];
    unsigned v = 0;
    for (int i = threadIdx.x; i < 65536; i += BLK)
        if (i & 3) v |= m[i];
    #pragma unroll
    for (int off = 32; off; off >>= 1) v |= __shfl_down(v, off);
    if ((threadIdx.x & 63) == 0) sh[threadIdx.x >> 6] = v;
    __syncthreads();
    if (threadIdx.x == 0) {
        unsigned r = 0;
        #pragma unroll
        for (int w = 0; w < WAVES; ++w) r |= sh[w];
        *flag = (r == 0) ? 1 : 0;   // 1 => int32 layout
    }
}

// --------------------------------------------------------------------------
#define MASK_I32 { int4 q = ((const int4*)mp)[e]; \
    m0 = q.x ? 1.f : 0.f; m1 = q.y ? 1.f : 0.f; m2 = q.z ? 1.f : 0.f; m3 = q.w ? 1.f : 0.f; }
#define MASK_U8  { uchar4 q = ((const uchar4*)mp)[e]; \
    m0 = q.x ? 1.f : 0.f; m1 = q.y ? 1.f : 0.f; m2 = q.z ? 1.f : 0.f; m3 = q.w ? 1.f : 0.f; }

#define P1_COMP(MJ, GX, RX, VX, LX, ZX, C0, C1, C2, C3, C4)      \
    do {                                                         \
        GX = fmaf(GAMMA_F, GX, RX);                              \
        float mm = (MJ);                                         \
        float Gm = mm * GX, vm = mm * VX, lm = mm * LX, mw = mm * w; \
        a0 += mm; a1 += Gm;                                      \
        a2 = fmaf(Gm, GX, a2); a3 = fmaf(Gm, VX, a3);            \
        a4 += vm; a5 = fmaf(vm, VX, a5);                         \
        a6 = fmaf(lm, GX, a6); a7 += lm;                         \
        a8 = fmaf(mm, ZX, a8); a9 = fmaf(lm, VX, a9);            \
        C0 += mw;                                                \
        C1 = fmaf(mw, GX, C1);                                   \
        C2 = fmaf(mw, w,  C2);                                   \
        C3 = fmaf(mw, VX, C3);                                   \
        C4 = fmaf(mw, LX, C4);                                   \
    } while (0)

#define P1_ITER(MASKLOAD)                                        \
    _Pragma("unroll 4")                                          \
    for (int i = L - 1; i >= 0; --i) {                           \
        int e = base + i * B4;                                   \
        float4 r = rw[e], v = vv[e], l = lq[e], z = en[e];       \
        float m0, m1, m2, m3;                                    \
        MASKLOAD;                                                \
        P1_COMP(m0, G.x, r.x, v.x, l.x, z.x, c0.x, c1.x, c2.x, c3.x, c4.x); \
        P1_COMP(m1, G.y, r.y, v.y, l.y, z.y, c0.y, c1.y, c2.y, c3.y, c4.y); \
        P1_COMP(m2, G.z, r.z, v.z, l.z, z.z, c0.z, c1.z, c2.z, c3.z, c4.z); \
        P1_COMP(m3, G.w, r.w, v.w, l.w, z.w, c0.w, c1.w, c2.w, c3.w, c4.w); \
        w *= GAMMA_F;                                            \
    }

template<int L>
__global__ void __launch_bounds__(BLK) k_pass1(
    const float4* __restrict__ rw, const float4* __restrict__ vv,
    const float4* __restrict__ lq, const float4* __restrict__ en,
    const void*  __restrict__ mp, const int* __restrict__ flag,
    float4* __restrict__ S,  float4* __restrict__ K0, float4* __restrict__ K1,
    float4* __restrict__ K2, float4* __restrict__ K3, float4* __restrict__ K4,
    double* __restrict__ partials)
{
    int idx = blockIdx.x * BLK + threadIdx.x;
    int c = idx / B4;
    int b = idx - c * B4;
    int base = c * L * B4 + b;

    float4 G  = make_float4(0.f, 0.f, 0.f, 0.f);
    float4 c0 = G, c1 = G, c2 = G, c3 = G, c4 = G;
    float a0 = 0.f, a1 = 0.f, a2 = 0.f, a3 = 0.f, a4 = 0.f;
    float a5 = 0.f, a6 = 0.f, a7 = 0.f, a8 = 0.f, a9 = 0.f;
    float w = GAMMA_F;

    if (*flag) { P1_ITER(MASK_I32); } else { P1_ITER(MASK_U8); }

    S[idx] = G;
    K0[idx] = c0; K1[idx] = c1; K2[idx] = c2; K3[idx] = c3; K4[idx] = c4;

    // deterministic block reduction of the 10 base sums, f64
    double d[10] = {a0, a1, a2, a3, a4, a5, a6, a7, a8, a9};
    #pragma unroll
    for (int k = 0; k < 10; ++k)
        #pragma unroll
        for (int off = 32; off; off >>= 1)
            d[k] += __shfl_down(d[k], off);

    __shared__ double sh[WAVES][10];
    int lane = threadIdx.x & 63, wv = threadIdx.x >> 6;
    if (lane == 0) {
        #pragma unroll
        for (int k = 0; k < 10; ++k) sh[wv][k] = d[k];
    }
    __syncthreads();
    if (threadIdx.x == 0) {
        #pragma unroll
        for (int k = 0; k < 10; ++k) {
            double s = sh[0][k];
            #pragma unroll
            for (int ww = 1; ww < WAVES; ++ww) s += sh[ww][k];
            partials[(size_t)blockIdx.x * 10 + k] = s;
        }
    }
}

// --------------------------------------------------------------------------
// Per (group, column): group carry Sg and response coefficients.
//   corr0 (->SG ), corr2 (->SGv), corr3 (->SlpG): A + H*B     (linear)
//   corr1 (->SG2):                               A + H*B + H^2*C
template<int L>
__global__ void __launch_bounds__(BLK) k_pass2a(
    const float* __restrict__ S,  const float* __restrict__ K0,
    const float* __restrict__ K1, const float* __restrict__ K2,
    const float* __restrict__ K3, const float* __restrict__ K4,
    float* __restrict__ P2)     // 10 planes of GCB floats: Sg,A0..A3,B0..B3,C1
{
    constexpr int NC = T / L;
    constexpr int NG = NC / GC;
    constexpr float GL = (float)cpow(0.99, L);
    static_assert(NG * GC == NC, "group split");

    int tid = blockIdx.x * BLK + threadIdx.x;   // 0 .. GCB-1
    int g = tid / B;
    int col = tid - g * B;

    float h = 0.f, w2 = 1.f;
    float A0 = 0.f, A1 = 0.f, A2 = 0.f, A3 = 0.f;
    float Bb0 = 0.f, Bb1 = 0.f, Bb2 = 0.f, Bb3 = 0.f, Cc = 0.f;

    #pragma unroll 4
    for (int j = NG - 1; j >= 0; --j) {
        int e = (g * NG + j) * B + col;
        float s  = S[e];
        float k0 = K0[e], k1 = K1[e], k2 = K2[e], k3 = K3[e], k4 = K4[e];
        A0  = fmaf(h, k0, A0);
        A1  = fmaf(h, fmaf(h, k2, 2.f * k1), A1);
        A2  = fmaf(h, k3, A2);
        A3  = fmaf(h, k4, A3);
        Bb0 = fmaf(w2, k0, Bb0);
        Bb1 = fmaf(2.f * w2, fmaf(h, k2, k1), Bb1);
        Bb2 = fmaf(w2, k3, Bb2);
        Bb3 = fmaf(w2, k4, Bb3);
        Cc  = fmaf(w2 * w2, k2, Cc);
        h = fmaf(GL, h, s);
        w2 *= GL;
    }
    P2[0 * GCB + tid] = h;    // group aggregate Sg
    P2[1 * GCB + tid] = A0; P2[2 * GCB + tid] = A1;
    P2[3 * GCB + tid] = A2; P2[4 * GCB + tid] = A3;
    P2[5 * GCB + tid] = Bb0; P2[6 * GCB + tid] = Bb1;
    P2[7 * GCB + tid] = Bb2; P2[8 * GCB + tid] = Bb3;
    P2[9 * GCB + tid] = Cc;
}

// --------------------------------------------------------------------------
__global__ void __launch_bounds__(BLK) k_pass2b(const float* __restrict__ P2,
                                                double* __restrict__ partials2)
{
    int col = blockIdx.x * BLK + threadIdx.x;   // 0..B-1
    double corr0 = 0.0, corr1 = 0.0, corr2 = 0.0, corr3 = 0.0;
    float H = 0.f;
    #pragma unroll 8
    for (int g = GC - 1; g >= 0; --g) {
        int e = g * B + col;
        float Sg = P2[0 * GCB + e];
        float A0 = P2[1 * GCB + e], A1 = P2[2 * GCB + e];
        float A2 = P2[3 * GCB + e], A3 = P2[4 * GCB + e];
        float B0 = P2[5 * GCB + e], B1 = P2[6 * GCB + e];
        float B2 = P2[7 * GCB + e], B3 = P2[8 * GCB + e];
        float Cc = P2[9 * GCB + e];
        double Hd = (double)H;
        corr0 += (double)A0 + Hd * B0;
        corr1 += (double)A1 + Hd * B1 + Hd * Hd * Cc;
        corr2 += (double)A2 + Hd * B2;
        corr3 += (double)A3 + Hd * B3;
        H = fmaf(GLNG, H, Sg);
    }

    double d[4] = {corr0, corr1, corr2, corr3};
    #pragma unroll
    for (int k = 0; k < 4; ++k)
        #pragma unroll
        for (int off = 32; off; off >>= 1)
            d[k] += __shfl_down(d[k], off);

    __shared__ double sh[WAVES][4];
    int lane = threadIdx.x & 63, wv = threadIdx.x >> 6;
    if (lane == 0) {
        #pragma unroll
        for (int k = 0; k < 4; ++k) sh[wv][k] = d[k];
    }
    __syncthreads();
    if (threadIdx.x == 0) {
        #pragma unroll
        for (int k = 0; k < 4; ++k) {
            double s = sh[0][k];
            #pragma unroll
            for (int ww = 1; ww < WAVES; ++ww) s += sh[ww][k];
            partials2[(size_t)blockIdx.x * 4 + k] = s;
        }
    }
}

// --------------------------------------------------------------------------
__global__ void __launch_bounds__(BLK) k_final(const double* __restrict__ partials,
                                               int nb1,
                                               const double* __restrict__ partials2,
                                               float* __restrict__ out)
{
    double d[10];
    #pragma unroll
    for (int k = 0; k < 10; ++k) d[k] = 0.0;
    for (int i = threadIdx.x; i < nb1; i += BLK) {
        #pragma unroll
        for (int k = 0; k < 10; ++k) d[k] += partials[(size_t)i * 10 + k];
    }
    double e4[4] = {0.0, 0.0, 0.0, 0.0};
    if (threadIdx.x < NB2) {
        #pragma unroll
        for (int k = 0; k < 4; ++k) e4[k] = partials2[(size_t)threadIdx.x * 4 + k];
    }

    #pragma unroll
    for (int k = 0; k < 10; ++k)
        #pragma unroll
        for (int off = 32; off; off >>= 1)
            d[k] += __shfl_down(d[k], off);
    #pragma unroll
    for (int k = 0; k < 4; ++k)
        #pragma unroll
        for (int off = 32; off; off >>= 1)
            e4[k] += __shfl_down(e4[k], off);

    __shared__ double sh[WAVES][10];
    __shared__ double sh2[WAVES][4];
    int lane = threadIdx.x & 63, wv = threadIdx.x >> 6;
    if (lane == 0) {
        #pragma unroll
        for (int k = 0; k < 10; ++k) sh[wv][k] = d[k];
        #pragma unroll
        for (int k = 0; k < 4; ++k) sh2[wv][k] = e4[k];
    }
    __syncthreads();
    if (threadIdx.x == 0) {
        double s[10], c4[4];
        #pragma unroll
        for (int k = 0; k < 10; ++k) {
            double t = sh[0][k];
            #pragma unroll
            for (int ww = 1; ww < WAVES; ++ww) t += sh[ww][k];
            s[k] = t;
        }
        #pragma unroll
        for (int k = 0; k < 4; ++k) {
            double t = sh2[0][k];
            #pragma unroll
            for (int ww = 1; ww < WAVES; ++ww) t += sh2[ww][k];
            c4[k] = t;
        }

        double n   = s[0];
        double SG  = s[1] + c4[0];
        double SG2 = s[2] + c4[1];
        double SGv = s[3] + c4[2];
        double Sv  = s[4];
        double Sv2 = s[5];
        double SlpG = s[6] + c4[3];
        double Slp = s[7];
        double Sent = s[8];
        double Slpv = s[9];

        double mean = SG / n;
        double css  = SG2 - 2.0 * mean * SG + mean * mean * n;   // sum m*(G-mean)^2
        double var  = css / (n - 1.0);
        double sd   = sqrt(var);
        double sc   = 1.0 / (sd + 1e-8);

        double critic = sc * sc * css - 2.0 * sc * (SGv - mean * Sv) + Sv2;
        double actor  = -sc * (SlpG - mean * Slp) + Slpv - 0.01 * Sent;

        out[0] = (float)critic;
        out[1] = (float)actor;
    }
}

// --------------------------------------------------------------------------
template<int L>
static void run_pipeline(void* const* d_in, void* d_out, char* ws, hipStream_t stream) {
    constexpr int NC   = T / L;
    constexpr int NCB4 = NC * B4;
    constexpr int NB1  = NCB4 / BLK;

    size_t off = 0;
    float4* S  = (float4*)(ws + off); off += (size_t)NCB4 * 16;
    float4* K0 = (float4*)(ws + off); off += (size_t)NCB4 * 16;
    float4* K1 = (float4*)(ws + off); off += (size_t)NCB4 * 16;
    float4* K2 = (float4*)(ws + off); off += (size_t)NCB4 * 16;
    float4* K3 = (float4*)(ws + off); off += (size_t)NCB4 * 16;
    float4* K4 = (float4*)(ws + off); off += (size_t)NCB4 * 16;
    float*  P2 = (float*) (ws + off); off += (size_t)10 * GCB * 4;
    double* p1 = (double*)(ws + off); off += (size_t)NB1 * 10 * 8;
    double* p2 = (double*)(ws + off); off += (size_t)NB2 * 4 * 8;
    int*  flag = (int*)  (ws + off);

    const float4* rw = (const float4*)d_in[0];
    const float4* vv = (const float4*)d_in[1];
    const float4* lq = (const float4*)d_in[2];
    const float4* en = (const float4*)d_in[3];
    const void*   mp = d_in[4];

    k_detect<<<1, BLK, 0, stream>>>((const unsigned char*)mp, flag);
    k_pass1<L><<<NB1, BLK, 0, stream>>>(rw, vv, lq, en, mp, flag,
                                        S, K0, K1, K2, K3, K4, p1);
    k_pass2a<L><<<GCB / BLK, BLK, 0, stream>>>((const float*)S, (const float*)K0,
                                               (const float*)K1, (const float*)K2,
                                               (const float*)K3, (const float*)K4, P2);
    k_pass2b<<<NB2, BLK, 0, stream>>>(P2, p2);
    k_final<<<1, BLK, 0, stream>>>(p1, NB1, p2, (float*)d_out);
}

static size_t need(int L) {
    size_t NCB4 = (size_t)(T / L) * B4;
    return NCB4 * 16 * 6                 // S + K0..K4
         + (size_t)10 * GCB * 4          // pass2a planes
         + (NCB4 / BLK) * 10 * 8         // partials1
         + (size_t)NB2 * 4 * 8 + 64;     // partials2 + flag/pad
}

extern "C" void kernel_launch(void* const* d_in, const int* in_sizes, int n_in,
                              void* d_out, int out_size, void* d_ws, size_t ws_size,
                              hipStream_t stream) {
    char* ws = (char*)d_ws;
    if      (ws_size >= need(16))  run_pipeline<16>(d_in, d_out, ws, stream);
    else if (ws_size >= need(32))  run_pipeline<32>(d_in, d_out, ws, stream);
    else if (ws_size >= need(64))  run_pipeline<64>(d_in, d_out, ws, stream);
    else                           run_pipeline<128>(d_in, d_out, ws, stream);
}